// Round 5
// baseline (106.700 us; speedup 1.0000x reference)
//
#include <hip/hip_runtime.h>

#define IMG   128
#define KF    4
#define NF    800
#define NV    2000
#define NB    2
#define EPSF  1e-8f
#define BLURF 0.01f
// rect-edge cull: dist>0.1015 => (w/len)^2 > 0.0103 with w<0
#define CULL_D2 0.0103f
#define HEXT    0.0547f   // tile half-extent (7/128) + margin

typedef unsigned long long u64;
#define INVK ((((u64)0x7f800000u) << 32) | 0xffffffffu)   // z=+inf, idx=-1

// Match numpy: no FMA contraction anywhere on the exact paths.
#pragma clang fp contract(off)

__device__ __forceinline__ float seg_d2(float pax, float pay, float abx, float aby) {
#pragma clang fp contract(off)
    float dd = (abx * abx + aby * aby) + EPSF;
    float t  = (pax * abx + pay * aby) / dd;   // true IEEE divide
    t = fminf(fmaxf(t, 0.0f), 1.0f);
    float dx = pax - t * abx;
    float dy = pay - t * aby;
    return dx * dx + dy * dy;
}

__device__ __forceinline__ void ins4(u64& s0, u64& s1, u64& s2, u64& s3, u64 k) {
    bool c0 = k < s0, c1 = k < s1, c2 = k < s2, c3 = k < s3;
    s3 = c2 ? s2 : (c3 ? k : s3);
    s2 = c1 ? s1 : (c2 ? k : s2);
    s1 = c0 ? s0 : (c1 ? k : s1);
    s0 = c0 ? k  : s0;
}

__device__ __forceinline__ float bcastf(float v, int s) {
    return __uint_as_float((unsigned)__builtin_amdgcn_readlane(__float_as_uint(v), s));
}

// ---- kernel 1: one wave = one (tile, face-slice); no LDS, no barriers ----
__global__ __launch_bounds__(256, 4) void raster_p1(
    const float* __restrict__ verts,   // (B, V, 3)
    const int*   __restrict__ faces,   // (F, 3)
    u64* __restrict__ ws,              // [512*S][4][64] partial keys
    int sh)                            // log2(slices), S in {4,8,16}
{
#pragma clang fp contract(off)
    const int S     = 1 << sh;
    const int chunk = NF >> sh;
    const int tid   = threadIdx.x;
    const int wave  = tid >> 6;
    const int lane  = tid & 63;
    const int unit  = blockIdx.x * 4 + wave;   // [0, 512*S)
    const int tile  = unit >> sh;
    const int slice = unit & (S - 1);
    const int b     = tile >> 8;
    const int trow  = (tile & 255) >> 4;
    const int tcol  = tile & 15;
    const float* vb = verts + b * NV * 3;
    const int fbase = slice * chunk;

    // per-lane pixel geometry (8x8 tile)
    const int pr = lane >> 3, pc = lane & 7;
    const int row = trow * 8 + pr, col = tcol * 8 + pc;
    const float px = 1.0f - (2.0f * ((float)col + 0.5f)) / 128.0f;
    const float py = 1.0f - (2.0f * ((float)row + 0.5f)) / 128.0f;
    const float txmax = 1.0f - (2.0f * ((float)(tcol * 8)     + 0.5f)) / 128.0f;
    const float txmin = 1.0f - (2.0f * ((float)(tcol * 8 + 7) + 0.5f)) / 128.0f;
    const float tymax = 1.0f - (2.0f * ((float)(trow * 8)     + 0.5f)) / 128.0f;
    const float tymin = 1.0f - (2.0f * ((float)(trow * 8 + 7) + 0.5f)) / 128.0f;
    const float cx = 0.5f * (txmin + txmax);
    const float cy = 0.5f * (tymin + tymax);

    u64 s0 = INVK, s1 = INVK, s2 = INVK, s3 = INVK;

    for (int fo = 0; fo < chunk; fo += 64) {
        const int fl = fo + lane;           // local face index in slice
        bool surv = false;
        float a0x = 0, a0y = 0, a1x = 0, a1y = 0, a2x = 0, a2y = 0;
        float z0 = 0, z1 = 0, z2 = 0, denom = 1;
        if (fl < chunk) {
            const int f = fbase + fl;
            int i0 = faces[3 * f + 0], i1 = faces[3 * f + 1], i2 = faces[3 * f + 2];
            a0x = vb[3 * i0]; a0y = vb[3 * i0 + 1]; z0 = vb[3 * i0 + 2];
            a1x = vb[3 * i1]; a1y = vb[3 * i1 + 1]; z1 = vb[3 * i1 + 2];
            a2x = vb[3 * i2]; a2y = vb[3 * i2 + 1]; z2 = vb[3 * i2 + 2];
            // numpy op order for area (exact-match)
            float area = (a2x - a0x) * (a1y - a0y) - (a2y - a0y) * (a1x - a0x);
            float aab  = fabsf(area);
            denom = (aab > EPSF) ? area : (area >= 0.0f ? EPSF : -EPSF);
            surv = aab > EPSF;
            float bxmin = fminf(a0x, fminf(a1x, a2x)) - 0.101f;
            float bxmax = fmaxf(a0x, fmaxf(a1x, a2x)) + 0.101f;
            float bymin = fminf(a0y, fminf(a1y, a2y)) - 0.101f;
            float bymax = fmaxf(a0y, fmaxf(a1y, a2y)) + 0.101f;
            surv &= !(bxmin > txmax || bxmax < txmin || bymin > tymax || bymax < tymin);
            // exact rect-vs-edge-line cull (conservative)
            float s = (area >= 0.0f) ? 1.0f : -1.0f;
            float e0x = a2x - a1x, e0y = a2y - a1y;
            float e1x = a0x - a2x, e1y = a0y - a2y;
            float e2x = a1x - a0x, e2y = a1y - a0y;
            float w0 = s * ((cx - a1x) * e0y - (cy - a1y) * e0x) + HEXT * (fabsf(e0x) + fabsf(e0y));
            float w1 = s * ((cx - a2x) * e1y - (cy - a2y) * e1x) + HEXT * (fabsf(e1x) + fabsf(e1y));
            float w2 = s * ((cx - a0x) * e2y - (cy - a0y) * e2x) + HEXT * (fabsf(e2x) + fabsf(e2y));
            float l0 = e0x * e0x + e0y * e0y;
            float l1 = e1x * e1x + e1y * e1y;
            float l2 = e2x * e2x + e2y * e2y;
            surv &= !((w0 < 0.0f) & (w0 * w0 > CULL_D2 * l0));
            surv &= !((w1 < 0.0f) & (w1 * w1 > CULL_D2 * l1));
            surv &= !((w2 < 0.0f) & (w2 * w2 > CULL_D2 * l2));
        }
        u64 mask = __ballot(surv);
        while (mask) {
            const int sl = (int)__builtin_ctzll(mask);   // scalar survivor lane
            mask &= mask - 1;
            // broadcast the surviving lane's face data (v_readlane: VALU-only)
            float A0x = bcastf(a0x, sl), A0y = bcastf(a0y, sl);
            float A1x = bcastf(a1x, sl), A1y = bcastf(a1y, sl);
            float A2x = bcastf(a2x, sl), A2y = bcastf(a2y, sl);
            float Z0  = bcastf(z0, sl),  Z1  = bcastf(z1, sl);
            float Z2  = bcastf(z2, sl),  D   = bcastf(denom, sl);
            const int fg = fbase + fo + sl;
            float e0x = A2x - A1x, e0y = A2y - A1y;   // a1->a2
            float e1x = A0x - A2x, e1y = A0y - A2y;   // a2->a0
            float e2x = A1x - A0x, e2y = A1y - A0y;   // a0->a1
            float p0x = px - A0x, p0y = py - A0y;
            float p1x = px - A1x, p1y = py - A1y;
            float p2x = px - A2x, p2y = py - A2y;
            float w0 = p1x * e0y - p1y * e0x;
            float w1 = p2x * e1y - p2y * e1x;
            float w2 = p0x * e2y - p0y * e2x;
            float b0 = w0 / D, b1 = w1 / D, b2 = w2 / D;    // IEEE divides
            float zpix = (b0 * Z0 + b1 * Z1) + b2 * Z2;     // numpy order
            bool inside = fminf(b0, fminf(b1, b2)) >= 0.0f; // no NaNs possible
            bool valid;
            if (__all(inside)) {
                valid = (zpix > EPSF);
            } else {
                float dA = seg_d2(p0x, p0y, e2x, e2y);   // (p,a0,a1)
                float dB = seg_d2(p1x, p1y, e0x, e0y);   // (p,a1,a2)
                float dC = seg_d2(p2x, p2y, e1x, e1y);   // (p,a2,a0)
                float dmin = fminf(dA, fminf(dB, dC));
                valid = (inside | (dmin < BLURF)) & (zpix > EPSF);
            }
            u64 key = valid ? ((((u64)__float_as_uint(zpix)) << 32) | (unsigned)fg) : INVK;
            if (__any(key < s3)) ins4(s0, s1, s2, s3, key);
        }
    }

    u64* wrow = ws + (size_t)unit * 256;
    wrow[0 * 64 + lane] = s0;
    wrow[1 * 64 + lane] = s1;
    wrow[2 * 64 + lane] = s2;
    wrow[3 * 64 + lane] = s3;
}

// ---------------- kernel 2: merge slices + exact epilogue ----------------
__global__ __launch_bounds__(256) void raster_p2(
    const float* __restrict__ verts,
    const int*   __restrict__ faces,
    const u64* __restrict__ ws,
    int sh,
    float* __restrict__ out0, float* __restrict__ out1,
    float* __restrict__ out2, float* __restrict__ out3)
{
#pragma clang fp contract(off)
    __shared__ u64 sK[4 * 64];
    const int S    = 1 << sh;
    const int tid  = threadIdx.x;
    const int tile = blockIdx.x;
    const int b    = tile >> 8;
    const int trow = (tile & 255) >> 4;
    const int tcol = tile & 15;
    const float* vb = verts + b * NV * 3;

    if (tid < 64) {
        u64 s0 = INVK, s1 = INVK, s2 = INVK, s3 = INVK;
        const u64* base = ws + (size_t)tile * S * 256;
        for (int s = 0; s < S; ++s) {
            ins4(s0, s1, s2, s3, base[s * 256 + 0 * 64 + tid]);
            ins4(s0, s1, s2, s3, base[s * 256 + 1 * 64 + tid]);
            ins4(s0, s1, s2, s3, base[s * 256 + 2 * 64 + tid]);
            ins4(s0, s1, s2, s3, base[s * 256 + 3 * 64 + tid]);
        }
        sK[0 * 64 + tid] = s0;
        sK[1 * 64 + tid] = s1;
        sK[2 * 64 + tid] = s2;
        sK[3 * 64 + tid] = s3;
    }
    __syncthreads();

    int pix = tid >> 2, k = tid & 3;
    u64 key = sK[k * 64 + pix];
    int prow = pix >> 3, pcol = pix & 7;
    int grow = trow * 8 + prow, gcol = tcol * 8 + pcol;
    int p = (b * IMG + grow) * IMG + gcol;
    float qx = 1.0f - (2.0f * ((float)gcol + 0.5f)) / 128.0f;
    float qy = 1.0f - (2.0f * ((float)grow + 0.5f)) / 128.0f;
    float o0 = -1.0f, o1 = -1.0f, ob0 = -1.0f, ob1 = -1.0f, ob2 = -1.0f, o3 = -1.0f;
    if ((unsigned)(key >> 32) != 0x7f800000u) {
        int fi = (int)(unsigned)(key & 0xffffffffu);
        int i0 = faces[3 * fi + 0], i1 = faces[3 * fi + 1], i2 = faces[3 * fi + 2];
        float a0x = vb[3 * i0], a0y = vb[3 * i0 + 1], z0 = vb[3 * i0 + 2];
        float a1x = vb[3 * i1], a1y = vb[3 * i1 + 1], z1 = vb[3 * i1 + 2];
        float a2x = vb[3 * i2], a2y = vb[3 * i2 + 1], z2 = vb[3 * i2 + 2];
        float area = (a2x - a0x) * (a1y - a0y) - (a2y - a0y) * (a1x - a0x);
        float aab  = fabsf(area);
        float denom = (aab > EPSF) ? area : (area >= 0.0f ? EPSF : -EPSF);
        float e0x = a2x - a1x, e0y = a2y - a1y;
        float e1x = a0x - a2x, e1y = a0y - a2y;
        float e2x = a1x - a0x, e2y = a1y - a0y;
        float p0x = qx - a0x, p0y = qy - a0y;
        float p1x = qx - a1x, p1y = qy - a1y;
        float p2x = qx - a2x, p2y = qy - a2y;
        float w0 = p1x * e0y - p1y * e0x;
        float w1 = p2x * e1y - p2y * e1x;
        float w2 = p0x * e2y - p0y * e2x;
        float b0 = w0 / denom, b1 = w1 / denom, b2 = w2 / denom;
        float zpix = (b0 * z0 + b1 * z1) + b2 * z2;
        bool inside = (b0 >= 0.0f) & (b1 >= 0.0f) & (b2 >= 0.0f);
        float dA = seg_d2(p0x, p0y, e2x, e2y);
        float dB = seg_d2(p1x, p1y, e0x, e0y);
        float dC = seg_d2(p2x, p2y, e1x, e1y);
        float dmin = fminf(dA, fminf(dB, dC));
        o0 = (float)fi;
        o1 = zpix;
        ob0 = b0; ob1 = b1; ob2 = b2;
        o3 = inside ? -dmin : dmin;
    }
    int o = p * KF + k;
    out0[o] = o0;
    out1[o] = o1;
    out2[o * 3 + 0] = ob0;
    out2[o * 3 + 1] = ob1;
    out2[o * 3 + 2] = ob2;
    out3[o] = o3;
}

extern "C" void kernel_launch(void* const* d_in, const int* in_sizes, int n_in,
                              void* d_out, int out_size, void* d_ws, size_t ws_size,
                              hipStream_t stream) {
    const float* verts = (const float*)d_in[0];
    const int*   faces = (const int*)d_in[1];
    float* out = (float*)d_out;
    const int n0 = NB * IMG * IMG * KF;   // 131072 per (B,H,W,K) output

    // ws usage: 512*S units x 2 KB. Evidence (R4 poison fill): ws_size = 256 MB.
    const size_t per_unit = 256 * sizeof(u64);          // 2 KB
    int sh = (ws_size >= 512ull * 8 * per_unit) ? 3     // 8 slices of 100 (8 MB)
           : 2;                                         // 4 slices of 200 (4 MB)
    const int S = 1 << sh;

    raster_p1<<<dim3(512 * S / 4), dim3(256), 0, stream>>>(verts, faces, (u64*)d_ws, sh);
    raster_p2<<<dim3(512), dim3(256), 0, stream>>>(verts, faces, (const u64*)d_ws, sh,
        out,                 // pix_to_face
        out + n0,            // zbuf
        out + 2 * n0,        // bary
        out + 5 * n0);       // dsign
}